// Round 5
// baseline (445.777 us; speedup 1.0000x reference)
//
#include <hip/hip_runtime.h>
#include <hip/hip_cooperative_groups.h>

namespace cg = cooperative_groups;

#define NUM_BINS 256
#define HW 262144        // 512*512
#define NBATCH 64
#define BPB 16           // blocks per batch (cooperative kernel)
#define GRID (NBATCH * BPB)   // 1024 = 4 blocks/CU on 256 CUs
#define ITERS 16         // float4 iterations per thread -> 64 px/thread

// ---------------------------------------------------------------------------
// gray = clip(round(0.299*u8r + 0.587*u8g + 0.114*u8b), 0, 255)
// u8c  = clip(floor(xc*255), 0, 255)
// Bit-exact vs float32 reference: no FMA contraction, left-to-right
// association, rintf = round-half-to-even (jnp.round).  (verified absmax=0)
// ---------------------------------------------------------------------------
__device__ __forceinline__ int gray_px(float r, float g, float b) {
#pragma clang fp contract(off)
    float ur = fminf(fmaxf(floorf(r * 255.0f), 0.0f), 255.0f);
    float ug = fminf(fmaxf(floorf(g * 255.0f), 0.0f), 255.0f);
    float ub = fminf(fmaxf(floorf(b * 255.0f), 0.0f), 255.0f);
    float s = 0.299f * ur + 0.587f * ug + 0.114f * ub;   // (a+b)+c, no fma
    s = fminf(fmaxf(rintf(s), 0.0f), 255.0f);
    return (int)s;
}

// Sequential Otsu on a 256-bin hist (bit-exact fp32 cumsum semantics).
__device__ __forceinline__ int otsu_from_hist(const unsigned int* h) {
    const float invN = 1.0f / 262144.0f;   // exact: 2^-18
    float mu_t = 0.0f;
    for (int i = 0; i < NUM_BINS; ++i) {
#pragma clang fp contract(off)
        float p = (float)h[i] * invN;
        mu_t += (float)i * p;
    }
    float omega = 0.0f, mu = 0.0f, best = -3.0f;
    int bi = 0;
    for (int i = 0; i < NUM_BINS; ++i) {
#pragma clang fp contract(off)
        float p = (float)h[i] * invN;
        omega += p;
        mu += (float)i * p;
        float denom = omega * (1.0f - omega);
        float sig;
        if (denom > 1e-12f) {
            float d = mu_t * omega - mu;
            sig = (d * d) / fmaxf(denom, 1e-12f);
        } else {
            sig = -1.0f;
        }
        if (sig > best) { best = sig; bi = i; }
    }
    return bi;
}

// ---------------------------------------------------------------------------
// Fused cooperative kernel. 1024 blocks x 256 thr, 64 px/thread.
// Phase 1: gray (kept packed in regs) + per-wave LDS hists -> per-block
//          partial hist in ws (non-atomic, no init needed).
// grid.sync()
// Phase 2: sum 16 partials -> block hist; thread 0: sequential Otsu;
//          write int32 mask from register-held gray.
// ---------------------------------------------------------------------------
__global__ void __launch_bounds__(256, 4)
fused_otsu_k(const float* __restrict__ x, int* __restrict__ out,
             unsigned int* __restrict__ partial) {
    __shared__ unsigned int lh[4][NUM_BINS];   // per-wave sub-hists
    __shared__ unsigned int bh[NUM_BINS];      // batch hist (phase 2)
    __shared__ int th_s;
    const int t = threadIdx.x;
    const int wv = t >> 6;

#pragma unroll
    for (int w = 0; w < 4; ++w) lh[w][t] = 0u;
    __syncthreads();

    const int b   = blockIdx.x >> 4;   // batch
    const int sub = blockIdx.x & 15;   // chunk within batch
    const size_t base = (size_t)b * 3 * HW;
    const float4* xr = (const float4*)(x + base);
    const float4* xg = (const float4*)(x + base + HW);
    const float4* xb = (const float4*)(x + base + 2 * HW);

    unsigned int gpack[ITERS];         // fully unrolled -> static reg indexing
#pragma unroll
    for (int k = 0; k < ITERS; ++k) {
        const int vidx = (sub << 12) + (k << 8) + t;   // float4 idx in batch
        float4 r4 = xr[vidx];
        float4 g4 = xg[vidx];
        float4 b4 = xb[vidx];
        int g0 = gray_px(r4.x, g4.x, b4.x);
        int g1 = gray_px(r4.y, g4.y, b4.y);
        int g2 = gray_px(r4.z, g4.z, b4.z);
        int g3 = gray_px(r4.w, g4.w, b4.w);
        gpack[k] = (unsigned)g0 | ((unsigned)g1 << 8) |
                   ((unsigned)g2 << 16) | ((unsigned)g3 << 24);
        atomicAdd(&lh[wv][g0], 1u);
        atomicAdd(&lh[wv][g1], 1u);
        atomicAdd(&lh[wv][g2], 1u);
        atomicAdd(&lh[wv][g3], 1u);
    }
    __syncthreads();
    partial[((size_t)blockIdx.x << 8) + t] =
        lh[0][t] + lh[1][t] + lh[2][t] + lh[3][t];

    cg::this_grid().sync();

    // Phase 2: batch hist = sum of this batch's 16 partials (exact int sum).
    unsigned int s = 0;
    const unsigned int* pb = partial + (((size_t)b * BPB) << 8);
#pragma unroll
    for (int c = 0; c < BPB; ++c) s += pb[(c << 8) + t];
    bh[t] = s;
    __syncthreads();

    if (t == 0) th_s = otsu_from_hist(bh);
    __syncthreads();
    const int th = th_s;

    int4* ob = (int4*)(out + (size_t)b * HW);
#pragma unroll
    for (int k = 0; k < ITERS; ++k) {
        const int vidx = (sub << 12) + (k << 8) + t;
        const unsigned g = gpack[k];
        int4 o;
        o.x = ((int)(g & 255u)         > th) ? 1 : 0;
        o.y = ((int)((g >> 8) & 255u)  > th) ? 1 : 0;
        o.z = ((int)((g >> 16) & 255u) > th) ? 1 : 0;
        o.w = ((int)(g >> 24)          > th) ? 1 : 0;
        ob[vidx] = o;
    }
}

// ---------------------------------------------------------------------------
// Fallback path (proven passing in round 4): 4-kernel pipeline.
// ---------------------------------------------------------------------------
__global__ void init_hist_k(unsigned int* __restrict__ hist) {
    hist[(blockIdx.x << 8) + threadIdx.x] = 0u;
}

__global__ void __launch_bounds__(256)
gray_hist_k(const float* __restrict__ x, unsigned char* __restrict__ gray,
            unsigned int* __restrict__ hist) {
    __shared__ unsigned int lh[NUM_BINS];
    const int t = threadIdx.x;
    lh[t] = 0u;
    __syncthreads();
    const int b     = blockIdx.x >> 6;
    const int chunk = blockIdx.x & 63;
    const size_t base = (size_t)b * 3 * HW;
    const float4* xr = (const float4*)(x + base);
    const float4* xg = (const float4*)(x + base + HW);
    const float4* xb = (const float4*)(x + base + 2 * HW);
    uchar4* gout = (uchar4*)(gray + (size_t)b * HW);
#pragma unroll
    for (int i = 0; i < 4; ++i) {
        const int vidx = (chunk << 10) + (i << 8) + t;
        float4 r4 = xr[vidx];
        float4 g4 = xg[vidx];
        float4 b4 = xb[vidx];
        int g0 = gray_px(r4.x, g4.x, b4.x);
        int g1 = gray_px(r4.y, g4.y, b4.y);
        int g2 = gray_px(r4.z, g4.z, b4.z);
        int g3 = gray_px(r4.w, g4.w, b4.w);
        gout[vidx] = make_uchar4((unsigned char)g0, (unsigned char)g1,
                                 (unsigned char)g2, (unsigned char)g3);
        atomicAdd(&lh[g0], 1u);
        atomicAdd(&lh[g1], 1u);
        atomicAdd(&lh[g2], 1u);
        atomicAdd(&lh[g3], 1u);
    }
    __syncthreads();
    atomicAdd(&hist[(b << 8) + t], lh[t]);
}

__global__ void __launch_bounds__(64)
otsu_k(const unsigned int* __restrict__ hist, int* __restrict__ thr) {
    const int b = threadIdx.x;
    unsigned int h[1];  // dummy to keep signature simple
    (void)h;
    thr[b] = otsu_from_hist(hist + (b << 8));
}

__global__ void __launch_bounds__(256)
mask_gray_k(const unsigned char* __restrict__ gray, const int* __restrict__ thr,
            int* __restrict__ out) {
    const int b     = blockIdx.x >> 8;
    const int chunk = blockIdx.x & 255;
    const int vidx  = (chunk << 8) + threadIdx.x;
    const int th = thr[b];
    uchar4 g = ((const uchar4*)(gray + (size_t)b * HW))[vidx];
    int4 o;
    o.x = ((int)g.x > th) ? 1 : 0;
    o.y = ((int)g.y > th) ? 1 : 0;
    o.z = ((int)g.z > th) ? 1 : 0;
    o.w = ((int)g.w > th) ? 1 : 0;
    ((int4*)(out + (size_t)b * HW))[vidx] = o;
}

extern "C" void kernel_launch(void* const* d_in, const int* in_sizes, int n_in,
                              void* d_out, int out_size, void* d_ws, size_t ws_size,
                              hipStream_t stream) {
    const float* x = (const float*)d_in[0];
    int* out = (int*)d_out;
    unsigned char* ws = (unsigned char*)d_ws;

    // ws layout: [0,1MB) partial hists | [1MB,+64KB) hist | then thr
    unsigned int* partial = (unsigned int*)ws;
    unsigned int* hist = (unsigned int*)(ws + (1u << 20));
    int* thr = (int*)(ws + (1u << 20) + NBATCH * NUM_BINS * 4);

    void* args[] = { (void*)&x, (void*)&out, (void*)&partial };
    hipError_t err = hipLaunchCooperativeKernel((const void*)fused_otsu_k,
                                                dim3(GRID), dim3(256),
                                                args, 0, stream);
    if (err != hipSuccess) {
        // fallback: proven 4-kernel pipeline (gray staged after partials)
        unsigned char* gray = ws + (2u << 20);
        init_hist_k<<<NBATCH, NUM_BINS, 0, stream>>>(hist);
        gray_hist_k<<<NBATCH * 64, 256, 0, stream>>>(x, gray, hist);
        otsu_k<<<1, 64, 0, stream>>>(hist, thr);
        mask_gray_k<<<NBATCH * 256, 256, 0, stream>>>(gray, thr, out);
    }
}